// Round 10
// baseline (983.366 us; speedup 1.0000x reference)
//
#include <hip/hip_runtime.h>
#include <cstdint>
#include <cstddef>

typedef unsigned short u16;
typedef unsigned int   u32;

typedef __bf16 bf16x8 __attribute__((ext_vector_type(8)));
typedef float  f32x4  __attribute__((ext_vector_type(4)));

#define AS1C(p) ((const __attribute__((address_space(1))) void*)(p))
#define AS3(p)  ((__attribute__((address_space(3))) void*)(p))

// ---------------------------------------------------------------------------
// Hardcoded graph structure (derived from EDGES, SKELETON_DIST=2, pooling):
// 12 pooling groups; per-group input-joint block lists (85 slots total).
// Safety: prep still multiplies by the mask block value, so an extra block
// listed here would contribute exactly 0.
// ---------------------------------------------------------------------------
__constant__ int d_slot_jb[85] = {
  0,1,2,12,13,16,17,20,                 // g0  (8)
  0,1,2,3,4,5,8,9,12,16,20,            // g1  (11)
  1,2,3,4,5,8,9,                       // g2  (7)
  1,2,3,4,5,6,7,8,9,                   // g3  (9)
  4,5,6,7,                             // g4  (4)
  1,2,3,4,5,8,9,10,11,                 // g5  (9)
  8,9,10,11,                           // g6  (4)
  0,1,12,13,14,15,16,17,20,            // g7  (9)
  12,13,14,15,                         // g8  (4)
  0,1,12,13,16,17,18,19,20,            // g9  (9)
  16,17,18,19,                         // g10 (4)
  0,1,2,12,13,16,17                    // g11 (7)
};
__constant__ int   d_gs0[12]    = {0,8,19,26,35,39,48,52,61,65,74,78};
__constant__ int   d_gnb[12]    = {8,11,7,9,4,9,4,9,4,9,4,7};
__constant__ int   d_gj0[12]    = {0,1,3,4,6,8,10,12,14,16,18,20};
__constant__ int   d_gj1[12]    = {-1,2,-1,5,7,9,11,13,15,17,19,-1};
__constant__ float d_gscale[12] = {1.f,0.5f,1.f,0.5f,0.5f,0.5f,0.5f,0.5f,0.5f,0.5f,0.5f,1.f};
// heavy groups first to reduce tail imbalance
__constant__ int   d_sched[12]  = {1,3,5,7,9,0,2,11,4,6,8,10};

static __device__ __forceinline__ u16 f2bf(float f) {
  union { float f; u32 u; } v; v.f = f;
  u32 r = v.u + 0x7fffu + ((v.u >> 16) & 1u);   // RNE
  return (u16)(r >> 16);
}

// ---------------------------------------------------------------------------
// Fused prep kernel: blocks [0,2720) = weights, [2720,24308) = x-pad (21588
// blocks = 8*1344*514 threads EXACTLY — round-5 bug was 4 blocks short),
// [24308,24314) = bias. All three parts independent; fusing removes two
// launch gaps and surfaces prep cost as one profilable dispatch.
// ---------------------------------------------------------------------------
__global__ void prep_all(const float* __restrict__ x, const float* __restrict__ wt,
                         const float* __restrict__ msk, const float* __restrict__ bias,
                         u16* __restrict__ xp, u16* __restrict__ apk,
                         float* __restrict__ bg) {
  const int blk = blockIdx.x;
  if (blk < 2720) {
    // ---- weights: packed folded A in per-chunk fragment-image order:
    // apk[u][c32=kk/32][m=0..127][kkl=kk%32] bf16 (8 KB per chunk), kk=c*16+tap
    int gid = blk * 256 + threadIdx.x;
    if (gid >= 85 * 8192) return;
    int u   = gid >> 13;
    int rem = gid & 8191;
    int m   = rem >> 6;
    int c   = rem & 63;
    int g = 11;
#pragma unroll
    for (int gg = 0; gg < 11; ++gg)
      if (u >= d_gs0[gg] && u < d_gs0[gg + 1]) g = gg;
    int jb = d_slot_jb[u];
    int j0 = d_gj0[g], j1 = d_gj1[g];
    float sc = d_gscale[g];
    float m0 = msk[((size_t)(j0 * 128) * 1344 + jb * 64) * 15];
    float m1 = (j1 >= 0) ? msk[((size_t)(j1 * 128) * 1344 + jb * 64) * 15] : 0.f;
    const float* w0 = wt + ((size_t)(j0 * 128 + m) * 1344 + jb * 64 + c) * 15;
    const float* w1 = (j1 >= 0) ? wt + ((size_t)(j1 * 128 + m) * 1344 + jb * 64 + c) * 15 : w0;
    u16 v[16];
#pragma unroll
    for (int k = 0; k < 15; ++k) {
      float a = m0 * w0[k] + m1 * w1[k];
      v[k] = f2bf(a * sc);
    }
    v[15] = 0;
    uint4* dst = (uint4*)(apk + (size_t)u * 131072 + (c >> 1) * 4096 + m * 32 + (c & 1) * 16);
    dst[0] = ((const uint4*)v)[0];
    dst[1] = ((const uint4*)v)[1];
  } else if (blk < 24308) {
    // ---- x: (8,1344,4096) fp32 -> reflect-padded bf16 xp (8,1344,4112 pitch)
    int gid = (blk - 2720) * 256 + threadIdx.x;
    if (gid >= 8 * 1344 * 514) return;
    int pc  = gid % 514;
    int row = gid / 514;
    int p   = pc * 8;
    const float* xr = x + (size_t)row * 4096;
    u16 v[8];
#pragma unroll
    for (int e = 0; e < 8; ++e) {
      int j = p + e - 7;
      j = j < 0 ? -j : (j > 4095 ? 8190 - j : j);
      v[e] = f2bf(xr[j]);
    }
    *(uint4*)(xp + (size_t)row * 4112 + p) = *(const uint4*)v;
  } else {
    // ---- pooled bias (1536)
    int pc = (blk - 24308) * 256 + threadIdx.x;
    if (pc >= 1536) return;
    int g = pc >> 7, m = pc & 127;
    float v = bias[d_gj0[g] * 128 + m];
    if (d_gj1[g] >= 0) v += bias[d_gj1[g] * 128 + m];
    bg[pc] = v * d_gscale[g];
  }
}

// ---------------------------------------------------------------------------
// Main: per WG one (group g, batch b, 128-wide t-tile); 128x128 out tile,
// 4 waves each 64x64 (4x4 MFMA 16x16x32 bf16).
// A-operand: double-buffered 8 KB kk=32 chunks in LDS, staged 2 chunks ahead
// via global_load_lds with inline-asm COUNTED s_waitcnt vmcnt(2) + raw
// s_barrier (T3+T4): the in-flight chunk is never drained, so its latency
// hides under a full chunk of MFMA. sched_barrier(0) pins the phases so the
// compiler cannot re-collapse the pipeline (rounds 2/4 lesson: plain loads
// get re-sunk; the intrinsic + asm waits cannot be).
// LDS A layout: row m (64 B), seg s stored at sloc = s ^ ((m>>1)&3) via
// pre-swizzled global source (swizzle on both sides, linear gload dest).
// B-operand: xs tile (64 ch x 272 pos bf16) in LDS, read-only per slot.
// ---------------------------------------------------------------------------
static __device__ __forceinline__ void stage_a(const u16* __restrict__ src,
                                               char* dst, int tid) {
  const int w = tid >> 6;
#pragma unroll
  for (int ii = 0; ii < 2; ++ii) {
    const int seg = ii * 256 + tid;          // LDS linear 16B-seg index
    const int m   = seg >> 2;                // row (0..127)
    const int s   = (seg & 3) ^ ((m >> 1) & 3);  // data seg living at this slot
    __builtin_amdgcn_global_load_lds(AS1C(src + m * 32 + s * 8),
                                     AS3(dst + ii * 4096 + w * 1024), 16, 0, 0);
  }
}

static __device__ __forceinline__ void compute_chunk_lds(
    const char* __restrict__ abase, const u32* __restrict__ xr32, int c32,
    f32x4 acc[4][4]) {
  bf16x8 af[4];
#pragma unroll
  for (int mt = 0; mt < 4; ++mt)
    af[mt] = *(const bf16x8*)(abase + mt * 1024);
#pragma unroll
  for (int nt = 0; nt < 4; ++nt) {
    union { u32 u[4]; bf16x8 v; } bb;
#pragma unroll
    for (int ww = 0; ww < 4; ++ww)
      bb.u[ww] = xr32[c32 * 280 + nt * 16 + ww];   // imm offsets (c32 static)
#pragma unroll
    for (int mt = 0; mt < 4; ++mt)
      acc[mt][nt] = __builtin_amdgcn_mfma_f32_16x16x32_bf16(af[mt], bb.v, acc[mt][nt], 0, 0, 0);
  }
}

__global__ __launch_bounds__(256, 3)
void conv_main(const u16* __restrict__ xpbf, const u16* __restrict__ apk,
               const float* __restrict__ biasg, float* __restrict__ out) {
  __shared__ __align__(16) u16 xs[64 * 280];   // 35840 B
  __shared__ __align__(16) u16 as[2 * 4096];   // 2 x 8 KB A chunk buffers

  const int tid = threadIdx.x;
  const int l   = tid & 63, w = tid >> 6;
  const int q   = l >> 4, lm = l & 15;
  const int wm  = w & 1, wn = w >> 1;

  const int gidx = blockIdx.x >> 7;
  const int g    = d_sched[gidx];
  const int r    = blockIdx.x & 127;
  const int b    = r >> 4;
  const int tile = r & 15;
  const int t0   = tile << 7;
  const int p0   = t0 << 1;

  const int nb = d_gnb[g];
  const int s0 = d_gs0[g];

  f32x4 acc[4][4];
#pragma unroll
  for (int i = 0; i < 4; ++i)
#pragma unroll
    for (int j = 0; j < 4; ++j)
      acc[i][j] = (f32x4){0.f, 0.f, 0.f, 0.f};

  // A-fragment LDS read base: row m = wm*64+mt*16+lm, slot = q ^ ((m>>1)&3).
  // (wm*64+mt*16)>>1 is 0 mod 4 so the XOR term depends only on lm.
  const char* a0 = (const char*)as + (wm * 64 + lm) * 64 + ((q ^ ((lm >> 1) & 3)) << 4);
  const char* a1 = a0 + 8192;
  // B reads: crow = 2*c32 + (q>>1), pos byte 16*(q&1) + 4*n
  const u32* xr32 = (const u32*)(xs + (q >> 1) * 280 + (q & 1) * 8 + (wn * 64 + lm) * 2);

  const u16* ablk = apk + (size_t)s0 * 131072;
  // prologue: slot 0 chunks 0,1 in flight; the two xs-staging syncs drain them
  stage_a(ablk, (char*)as, tid);
  stage_a(ablk + 4096, (char*)as + 8192, tid);

  for (int s = 0; s < nb; ++s) {
    const int jb = d_slot_jb[s0 + s];
    __syncthreads();  // xs (and prev-slot as bufs) fully consumed
    {
      const u16* srow = xpbf + (size_t)(b * 1344 + jb * 64) * 4112 + p0;
      for (int i = tid; i < 64 * 34; i += 256) {
        int c  = i / 34;
        int sg = i - c * 34;
        uint4 v = *(const uint4*)(srow + (size_t)c * 4112 + sg * 8);
        *(uint4*)((char*)xs + c * 560 + sg * 16) = v;
      }
    }
    __syncthreads();  // xs + pending A stages visible (compiler drains vm/lgkm)

    const u16* nxt = (s + 1 < nb) ? ablk + 131072 : ablk;  // last slot: dummy
#pragma unroll
    for (int c = 0; c < 32; ++c) {
      compute_chunk_lds((c & 1) ? a1 : a0, xr32, c, acc);
      __builtin_amdgcn_sched_barrier(0);
      __builtin_amdgcn_s_barrier();          // all waves done reading buf[c&1]
      __builtin_amdgcn_sched_barrier(0);
      const u16* src = (c < 30) ? (ablk + (c + 2) * 4096) : (nxt + (c - 30) * 4096);
      stage_a(src, (char*)as + (c & 1) * 8192, tid);   // 2 loads, stays in flight
      asm volatile("s_waitcnt vmcnt(2)" ::: "memory"); // chunk c+1 landed; c+2 flies
      __builtin_amdgcn_sched_barrier(0);
      __builtin_amdgcn_s_barrier();          // c+1 visible to all waves
      __builtin_amdgcn_sched_barrier(0);
    }
    ablk = nxt;
  }
  asm volatile("s_waitcnt vmcnt(0)" ::: "memory");  // drain dummy tail stages

  // epilogue: bias + leaky relu, D layout: row=(q*4+reg), col=lm per 16x16 tile
  const float* bgp = biasg + g * 128 + wm * 64;
  float* outb = out + ((size_t)b * 1536 + g * 128 + wm * 64) * 2048 + t0 + wn * 64;
#pragma unroll
  for (int mt = 0; mt < 4; ++mt) {
    const f32x4 bv = *(const f32x4*)(bgp + mt * 16 + q * 4);
#pragma unroll
    for (int reg = 0; reg < 4; ++reg) {
      const float bias = bv[reg];
      const int m = mt * 16 + q * 4 + reg;
      float* orow = outb + (size_t)m * 2048 + lm;
#pragma unroll
      for (int nt = 0; nt < 4; ++nt) {
        float v = acc[mt][nt][reg] + bias;
        orow[nt * 16] = v < 0.f ? 0.2f * v : v;
      }
    }
  }
}

// ---------------------------------------------------------------------------
extern "C" void kernel_launch(void* const* d_in, const int* in_sizes, int n_in,
                              void* d_out, int out_size, void* d_ws, size_t ws_size,
                              hipStream_t stream) {
  (void)in_sizes; (void)n_in; (void)out_size; (void)ws_size;
  const float* x   = (const float*)d_in[0];
  const float* wt  = (const float*)d_in[1];
  const float* bs  = (const float*)d_in[2];
  const float* msk = (const float*)d_in[3];
  // d_in[4] (pool_w): structure hardcoded, values (1/len) folded via d_gscale.

  u16*   xpbf = (u16*)d_ws;                                   // 88,424,448 B
  u16*   apk  = (u16*)((char*)d_ws + 88424448);               // 22,282,240 B
  float* bg   = (float*)((char*)d_ws + 110706688);            //      6,144 B
  float* out  = (float*)d_out;

  prep_all<<<dim3(24314), dim3(256), 0, stream>>>(x, wt, msk, bs, xpbf, apk, bg);
  conv_main<<<dim3(1536), dim3(256), 0, stream>>>(xpbf, apk, bg, out);
}

// Round 12
// 871.170 us; speedup vs baseline: 1.1288x; 1.1288x over previous
//
#include <hip/hip_runtime.h>
#include <cstdint>
#include <cstddef>

typedef unsigned short u16;
typedef unsigned int   u32;

typedef __bf16 bf16x8 __attribute__((ext_vector_type(8)));
typedef float  f32x4  __attribute__((ext_vector_type(4)));

#define AS1C(p) ((const __attribute__((address_space(1))) void*)(p))
#define AS3(p)  ((__attribute__((address_space(3))) void*)(p))

// ---------------------------------------------------------------------------
// Hardcoded graph structure (derived from EDGES, SKELETON_DIST=2, pooling):
// 12 pooling groups; per-group input-joint block lists (85 slots total).
// Safety: prep_w still multiplies by the mask block value, so an extra block
// listed here would contribute exactly 0.
// ---------------------------------------------------------------------------
__constant__ int d_slot_jb[85] = {
  0,1,2,12,13,16,17,20,                 // g0  (8)
  0,1,2,3,4,5,8,9,12,16,20,            // g1  (11)
  1,2,3,4,5,8,9,                       // g2  (7)
  1,2,3,4,5,6,7,8,9,                   // g3  (9)
  4,5,6,7,                             // g4  (4)
  1,2,3,4,5,8,9,10,11,                 // g5  (9)
  8,9,10,11,                           // g6  (4)
  0,1,12,13,14,15,16,17,20,            // g7  (9)
  12,13,14,15,                         // g8  (4)
  0,1,12,13,16,17,18,19,20,            // g9  (9)
  16,17,18,19,                         // g10 (4)
  0,1,2,12,13,16,17                    // g11 (7)
};
__constant__ int   d_gs0[12]    = {0,8,19,26,35,39,48,52,61,65,74,78};
__constant__ int   d_gnb[12]    = {8,11,7,9,4,9,4,9,4,9,4,7};
__constant__ int   d_gj0[12]    = {0,1,3,4,6,8,10,12,14,16,18,20};
__constant__ int   d_gj1[12]    = {-1,2,-1,5,7,9,11,13,15,17,19,-1};
__constant__ float d_gscale[12] = {1.f,0.5f,1.f,0.5f,0.5f,0.5f,0.5f,0.5f,0.5f,0.5f,0.5f,1.f};
// heavy groups first to reduce tail imbalance
__constant__ int   d_sched[12]  = {1,3,5,7,9,0,2,11,4,6,8,10};

static __device__ __forceinline__ u16 f2bf(float f) {
  union { float f; u32 u; } v; v.f = f;
  u32 r = v.u + 0x7fffu + ((v.u >> 16) & 1u);   // RNE
  return (u16)(r >> 16);
}

// ---------------------------------------------------------------------------
// P1: x (8,1344,4096) fp32 -> reflect-padded bf16 xp (8,1344,4112 pitch)
// Interior fast path (validated correct in round 11's first-pass check).
// ---------------------------------------------------------------------------
__global__ void prep_x(const float* __restrict__ x, u16* __restrict__ xp) {
  int gid = blockIdx.x * 256 + threadIdx.x;          // 8*1344*514 threads
  if (gid >= 8 * 1344 * 514) return;
  int pc  = gid % 514;
  int row = gid / 514;
  int p   = pc * 8;
  const float* xr = x + (size_t)row * 4096;
  u16 v[8];
  if (p >= 8 && p <= 4088) {               // j = p-7..p, all interior
    const float* bse = xr + p - 7;
#pragma unroll
    for (int e = 0; e < 8; ++e) v[e] = f2bf(bse[e]);
  } else {
#pragma unroll
    for (int e = 0; e < 8; ++e) {
      int j = p + e - 7;
      j = j < 0 ? -j : (j > 4095 ? 8190 - j : j);
      v[e] = f2bf(xr[j]);
    }
  }
  *(uint4*)(xp + (size_t)row * 4112 + p) = *(const uint4*)v;
}

// ---------------------------------------------------------------------------
// P2: packed folded weights A[u][m=128][kk=1024] bf16 (R0 layout),
//     kk = c*16 + tap (tap 15 = zero pad), u = global block slot (85).
//     A = gscale * sum_{j in group} maskblk(j,jb) * weight[j*128+m][jb*64+c][tap]
// ---------------------------------------------------------------------------
__global__ void prep_w(const float* __restrict__ wt, const float* __restrict__ msk,
                       u16* __restrict__ apk) {
  int gid = blockIdx.x * 256 + threadIdx.x;          // 85*8192 threads
  if (gid >= 85 * 8192) return;
  int u   = gid >> 13;
  int rem = gid & 8191;
  int m   = rem >> 6;
  int c   = rem & 63;
  int g = 11;
#pragma unroll
  for (int gg = 0; gg < 11; ++gg)
    if (u >= d_gs0[gg] && u < d_gs0[gg + 1]) g = gg;
  int jb = d_slot_jb[u];
  int j0 = d_gj0[g], j1 = d_gj1[g];
  float sc = d_gscale[g];
  float m0 = msk[((size_t)(j0 * 128) * 1344 + jb * 64) * 15];
  float m1 = (j1 >= 0) ? msk[((size_t)(j1 * 128) * 1344 + jb * 64) * 15] : 0.f;
  const float* w0 = wt + ((size_t)(j0 * 128 + m) * 1344 + jb * 64 + c) * 15;
  const float* w1 = (j1 >= 0) ? wt + ((size_t)(j1 * 128 + m) * 1344 + jb * 64 + c) * 15 : w0;
  u16 v[16];
#pragma unroll
  for (int k = 0; k < 15; ++k) {
    float a = m0 * w0[k] + m1 * w1[k];
    v[k] = f2bf(a * sc);
  }
  v[15] = 0;
  uint4* dst = (uint4*)(apk + (size_t)u * 131072 + m * 1024 + c * 16);
  dst[0] = ((const uint4*)v)[0];
  dst[1] = ((const uint4*)v)[1];
}

// ---------------------------------------------------------------------------
// P3: pooled bias (1536)
// ---------------------------------------------------------------------------
__global__ void prep_b(const float* __restrict__ bias, float* __restrict__ bg) {
  int pc = blockIdx.x * 256 + threadIdx.x;
  if (pc >= 1536) return;
  int g = pc >> 7, m = pc & 127;
  float v = bias[d_gj0[g] * 128 + m];
  if (d_gj1[g] >= 0) v += bias[d_gj1[g] * 128 + m];
  bg[pc] = v * d_gscale[g];
}

// ---------------------------------------------------------------------------
// Main: R0-proven schedule (stage -> barrier-drain -> compute, 2 barriers per
// kk=64 chunk) + XCD-chunked blockIdx swizzle (T1). Default dispatch
// round-robins consecutive blocks across the 8 XCDs, so the 128 blocks
// sharing one group's A-panel (~2-2.8 MB) were spread over all 8 L2s ->
// apk re-fetched ~7x (FETCH 247 MB vs 110 ideal) and every per-chunk drain
// waited on L3/HBM latency. Chunked remap wg=(bid&7)*192+(bid>>3) gives each
// XCD 192 consecutive logical WGs (1.5 groups) -> A stays L2-resident; the
// drain becomes an L2-hit wait. Bijective (1536 = 8*192). No sync changes.
// ---------------------------------------------------------------------------
__global__ __launch_bounds__(256, 3)
void conv_main(const u16* __restrict__ xpbf, const u16* __restrict__ apk,
               const float* __restrict__ biasg, float* __restrict__ out) {
  __shared__ __align__(16) u16 xs[64 * 280];   // pitch 280 bf16 (560 B)
  __shared__ __align__(16) u16 as[128 * 64];   // 16 KB: rows m, 8 swizzled 16B segs

  const int tid = threadIdx.x;
  const int l   = tid & 63, w = tid >> 6;
  const int q   = l >> 4, lm = l & 15;
  const int wm  = w & 1, wn = w >> 1;

  // XCD-chunked swizzle: logical wg id such that each XCD (bid&7) gets a
  // contiguous chunk of 192 logical WGs.
  const int wg   = (blockIdx.x & 7) * 192 + (blockIdx.x >> 3);
  const int gidx = wg >> 7;
  const int g    = d_sched[gidx];
  const int r    = wg & 127;
  const int b    = r >> 4;
  const int tile = r & 15;
  const int t0   = tile << 7;
  const int p0   = t0 << 1;

  const int nb = d_gnb[g];
  const int s0 = d_gs0[g];

  f32x4 acc[4][4];
#pragma unroll
  for (int i = 0; i < 4; ++i)
#pragma unroll
    for (int j = 0; j < 4; ++j)
      acc[i][j] = (f32x4){0.f, 0.f, 0.f, 0.f};

  const int as_mb = tid >> 3;   // + ii*32
  const int as_sp = tid & 7;

  for (int s = 0; s < nb; ++s) {
    const int u  = s0 + s;
    const int jb = d_slot_jb[u];
    __syncthreads();  // xs from previous block fully consumed
    {
      const u16* srow = xpbf + (size_t)(b * 1344 + jb * 64) * 4112 + p0;
      for (int i = tid; i < 64 * 34; i += 256) {
        int c  = i / 34;
        int sg = i - c * 34;
        uint4 v = *(const uint4*)(srow + (size_t)c * 4112 + sg * 8);
        *(uint4*)((char*)xs + c * 560 + sg * 16) = v;
      }
    }
    const u16* ablk = apk + (size_t)u * 131072;
    for (int kc = 0; kc < 16; ++kc) {
      __syncthreads();  // prev chunk of `as` consumed; (kc==0) xs writes ordered
#pragma unroll
      for (int ii = 0; ii < 4; ++ii) {
        int m    = ii * 32 + as_mb;
        int sloc = as_sp ^ (m & 7);
        const u16* gp = ablk + m * 1024 + kc * 64 + sloc * 8;
        __builtin_amdgcn_global_load_lds(AS1C(gp),
                                         AS3((char*)as + ii * 4096 + w * 1024),
                                         16, 0, 0);
      }
      __syncthreads();  // as (and xs) visible
#pragma unroll
      for (int ks = 0; ks < 2; ++ks) {
        bf16x8 af[4];
#pragma unroll
        for (int mt = 0; mt < 4; ++mt) {
          int m  = wm * 64 + mt * 16 + lm;
          int sp = (ks * 4 + q) ^ (m & 7);
          af[mt] = *(const bf16x8*)((const char*)as + m * 128 + sp * 16);
        }
        const int crow = kc * 4 + ks * 2 + (q >> 1);
        const char* xrow = (const char*)xs + crow * 560 + 16 * (q & 1);
#pragma unroll
        for (int nt = 0; nt < 4; ++nt) {
          int n = wn * 64 + nt * 16 + lm;
          const char* bp = xrow + 4 * n;
          union { u32 u[4]; bf16x8 v; } bb;
#pragma unroll
          for (int ww = 0; ww < 4; ++ww)
            bb.u[ww] = *(const u32*)(bp + 4 * ww);
#pragma unroll
          for (int mt = 0; mt < 4; ++mt)
            acc[mt][nt] = __builtin_amdgcn_mfma_f32_16x16x32_bf16(
                af[mt], bb.v, acc[mt][nt], 0, 0, 0);
        }
      }
    }
  }

  // epilogue: bias + leaky relu, D layout: row=(q*4+reg), col=lm per 16x16 tile
  const float* bgp = biasg + g * 128 + wm * 64;
  float* outb = out + ((size_t)b * 1536 + g * 128 + wm * 64) * 2048 + t0 + wn * 64;
#pragma unroll
  for (int mt = 0; mt < 4; ++mt) {
    const f32x4 bv = *(const f32x4*)(bgp + mt * 16 + q * 4);
#pragma unroll
    for (int reg = 0; reg < 4; ++reg) {
      const float bias = bv[reg];
      const int m = mt * 16 + q * 4 + reg;
      float* orow = outb + (size_t)m * 2048 + lm;
#pragma unroll
      for (int nt = 0; nt < 4; ++nt) {
        float v = acc[mt][nt][reg] + bias;
        orow[nt * 16] = v < 0.f ? 0.2f * v : v;
      }
    }
  }
}

// ---------------------------------------------------------------------------
extern "C" void kernel_launch(void* const* d_in, const int* in_sizes, int n_in,
                              void* d_out, int out_size, void* d_ws, size_t ws_size,
                              hipStream_t stream) {
  (void)in_sizes; (void)n_in; (void)out_size; (void)ws_size;
  const float* x   = (const float*)d_in[0];
  const float* wt  = (const float*)d_in[1];
  const float* bs  = (const float*)d_in[2];
  const float* msk = (const float*)d_in[3];
  // d_in[4] (pool_w): structure hardcoded, values (1/len) folded via d_gscale.

  u16*   xpbf = (u16*)d_ws;                                   // 88,424,448 B
  u16*   apk  = (u16*)((char*)d_ws + 88424448);               // 22,282,240 B
  float* bg   = (float*)((char*)d_ws + 110706688);            //      6,144 B
  float* out  = (float*)d_out;

  prep_x<<<dim3(21588), dim3(256), 0, stream>>>(x, xpbf);
  prep_w<<<dim3(2720),  dim3(256), 0, stream>>>(wt, msk, apk);
  prep_b<<<dim3(6),     dim3(256), 0, stream>>>(bs, bg);
  conv_main<<<dim3(1536), dim3(256), 0, stream>>>(xpbf, apk, bg, out);
}

// Round 13
// 782.194 us; speedup vs baseline: 1.2572x; 1.1138x over previous
//
#include <hip/hip_runtime.h>
#include <cstdint>
#include <cstddef>

typedef unsigned short u16;
typedef unsigned int   u32;

typedef __bf16 bf16x8 __attribute__((ext_vector_type(8)));
typedef float  f32x4  __attribute__((ext_vector_type(4)));

#define AS1C(p) ((const __attribute__((address_space(1))) void*)(p))
#define AS3(p)  ((__attribute__((address_space(3))) void*)(p))

// ---------------------------------------------------------------------------
// Hardcoded graph structure (derived from EDGES, SKELETON_DIST=2, pooling):
// 12 pooling groups; per-group input-joint block lists (85 slots total).
// Safety: prep_w still multiplies by the mask block value, so an extra block
// listed here would contribute exactly 0.
// ---------------------------------------------------------------------------
__constant__ int d_slot_jb[85] = {
  0,1,2,12,13,16,17,20,                 // g0  (8)
  0,1,2,3,4,5,8,9,12,16,20,            // g1  (11)
  1,2,3,4,5,8,9,                       // g2  (7)
  1,2,3,4,5,6,7,8,9,                   // g3  (9)
  4,5,6,7,                             // g4  (4)
  1,2,3,4,5,8,9,10,11,                 // g5  (9)
  8,9,10,11,                           // g6  (4)
  0,1,12,13,14,15,16,17,20,            // g7  (9)
  12,13,14,15,                         // g8  (4)
  0,1,12,13,16,17,18,19,20,            // g9  (9)
  16,17,18,19,                         // g10 (4)
  0,1,2,12,13,16,17                    // g11 (7)
};
__constant__ int   d_gs0[12]    = {0,8,19,26,35,39,48,52,61,65,74,78};
__constant__ int   d_gnb[12]    = {8,11,7,9,4,9,4,9,4,9,4,7};
__constant__ int   d_gj0[12]    = {0,1,3,4,6,8,10,12,14,16,18,20};
__constant__ int   d_gj1[12]    = {-1,2,-1,5,7,9,11,13,15,17,19,-1};
__constant__ float d_gscale[12] = {1.f,0.5f,1.f,0.5f,0.5f,0.5f,0.5f,0.5f,0.5f,0.5f,0.5f,1.f};
// heavy groups first to reduce tail imbalance (balanced under default
// round-robin XCD dispatch — R12 showed chunked XCD affinity breaks balance)
__constant__ int   d_sched[12]  = {1,3,5,7,9,0,2,11,4,6,8,10};

static __device__ __forceinline__ u16 f2bf(float f) {
  union { float f; u32 u; } v; v.f = f;
  u32 r = v.u + 0x7fffu + ((v.u >> 16) & 1u);   // RNE
  return (u16)(r >> 16);
}

// ---------------------------------------------------------------------------
// P1: x (8,1344,4096) fp32 -> reflect-padded bf16 xp (8,1344,4112 pitch)
// Interior fast path (validated correct through all checks in round 12).
// ---------------------------------------------------------------------------
__global__ void prep_x(const float* __restrict__ x, u16* __restrict__ xp) {
  int gid = blockIdx.x * 256 + threadIdx.x;          // 8*1344*514 threads
  if (gid >= 8 * 1344 * 514) return;
  int pc  = gid % 514;
  int row = gid / 514;
  int p   = pc * 8;
  const float* xr = x + (size_t)row * 4096;
  u16 v[8];
  if (p >= 8 && p <= 4088) {               // j = p-7..p, all interior
    const float* bse = xr + p - 7;
#pragma unroll
    for (int e = 0; e < 8; ++e) v[e] = f2bf(bse[e]);
  } else {
#pragma unroll
    for (int e = 0; e < 8; ++e) {
      int j = p + e - 7;
      j = j < 0 ? -j : (j > 4095 ? 8190 - j : j);
      v[e] = f2bf(xr[j]);
    }
  }
  *(uint4*)(xp + (size_t)row * 4112 + p) = *(const uint4*)v;
}

// ---------------------------------------------------------------------------
// P2: packed folded weights A[u][m=128][kk=1024] bf16,
//     kk = c*16 + tap (tap 15 = zero pad), u = global block slot (85).
//     A = gscale * sum_{j in group} maskblk(j,jb) * weight[j*128+m][jb*64+c][tap]
// ---------------------------------------------------------------------------
__global__ void prep_w(const float* __restrict__ wt, const float* __restrict__ msk,
                       u16* __restrict__ apk) {
  int gid = blockIdx.x * 256 + threadIdx.x;          // 85*8192 threads
  if (gid >= 85 * 8192) return;
  int u   = gid >> 13;
  int rem = gid & 8191;
  int m   = rem >> 6;
  int c   = rem & 63;
  int g = 11;
#pragma unroll
  for (int gg = 0; gg < 11; ++gg)
    if (u >= d_gs0[gg] && u < d_gs0[gg + 1]) g = gg;
  int jb = d_slot_jb[u];
  int j0 = d_gj0[g], j1 = d_gj1[g];
  float sc = d_gscale[g];
  float m0 = msk[((size_t)(j0 * 128) * 1344 + jb * 64) * 15];
  float m1 = (j1 >= 0) ? msk[((size_t)(j1 * 128) * 1344 + jb * 64) * 15] : 0.f;
  const float* w0 = wt + ((size_t)(j0 * 128 + m) * 1344 + jb * 64 + c) * 15;
  const float* w1 = (j1 >= 0) ? wt + ((size_t)(j1 * 128 + m) * 1344 + jb * 64 + c) * 15 : w0;
  u16 v[16];
#pragma unroll
  for (int k = 0; k < 15; ++k) {
    float a = m0 * w0[k] + m1 * w1[k];
    v[k] = f2bf(a * sc);
  }
  v[15] = 0;
  uint4* dst = (uint4*)(apk + (size_t)u * 131072 + m * 1024 + c * 16);
  dst[0] = ((const uint4*)v)[0];
  dst[1] = ((const uint4*)v)[1];
}

// ---------------------------------------------------------------------------
// P3: pooled bias (1536)
// ---------------------------------------------------------------------------
__global__ void prep_b(const float* __restrict__ bias, float* __restrict__ bg) {
  int pc = blockIdx.x * 256 + threadIdx.x;
  if (pc >= 1536) return;
  int g = pc >> 7, m = pc & 127;
  float v = bias[d_gj0[g] * 128 + m];
  if (d_gj1[g] >= 0) v += bias[d_gj1[g] * 128 + m];
  bg[pc] = v * d_gscale[g];
}

// ---------------------------------------------------------------------------
// Main: R0-proven schedule, verbatim (best measured: 325 us @ 52% MfmaUtil).
// Per WG one (group g, batch b, 128-wide t-tile); 128x128 out tile,
// 4 waves each 64x64 (4x4 MFMA 16x16x32 bf16). K-loop over input-joint blocks
// (xs tile 64ch x 272 pos) x 16 chunks of kk=64 (A staged via global_load_lds
// with XOR-swizzled 16B segments; stage -> barrier -> compute).
// Measured floors: MFMA pipe ~146 us, LDS reads ~158 us (B is 4xb32/frag,
// structural to the 1x-duplication virtual-im2col xs layout) — combined duty
// at 325 us is near-saturated; 7 pipelining variants all regressed or raced.
// ---------------------------------------------------------------------------
__global__ __launch_bounds__(256, 3)
void conv_main(const u16* __restrict__ xpbf, const u16* __restrict__ apk,
               const float* __restrict__ biasg, float* __restrict__ out) {
  __shared__ __align__(16) u16 xs[64 * 280];   // pitch 280 bf16 (560 B)
  __shared__ __align__(16) u16 as[128 * 64];   // 16 KB: rows m, 8 swizzled 16B segs

  const int tid = threadIdx.x;
  const int l   = tid & 63, w = tid >> 6;
  const int q   = l >> 4, lm = l & 15;
  const int wm  = w & 1, wn = w >> 1;

  const int gidx = blockIdx.x >> 7;
  const int g    = d_sched[gidx];
  const int r    = blockIdx.x & 127;
  const int b    = r >> 4;
  const int tile = r & 15;
  const int t0   = tile << 7;
  const int p0   = t0 << 1;

  const int nb = d_gnb[g];
  const int s0 = d_gs0[g];

  f32x4 acc[4][4];
#pragma unroll
  for (int i = 0; i < 4; ++i)
#pragma unroll
    for (int j = 0; j < 4; ++j)
      acc[i][j] = (f32x4){0.f, 0.f, 0.f, 0.f};

  const int as_mb = tid >> 3;   // + ii*32
  const int as_sp = tid & 7;

  for (int s = 0; s < nb; ++s) {
    const int u  = s0 + s;
    const int jb = d_slot_jb[u];
    __syncthreads();  // xs from previous block fully consumed
    {
      const u16* srow = xpbf + (size_t)(b * 1344 + jb * 64) * 4112 + p0;
      for (int i = tid; i < 64 * 34; i += 256) {
        int c  = i / 34;
        int sg = i - c * 34;
        uint4 v = *(const uint4*)(srow + (size_t)c * 4112 + sg * 8);
        *(uint4*)((char*)xs + c * 560 + sg * 16) = v;
      }
    }
    const u16* ablk = apk + (size_t)u * 131072;
    for (int kc = 0; kc < 16; ++kc) {
      __syncthreads();  // prev chunk of `as` consumed; (kc==0) xs writes ordered
#pragma unroll
      for (int ii = 0; ii < 4; ++ii) {
        int m    = ii * 32 + as_mb;
        int sloc = as_sp ^ (m & 7);
        const u16* gp = ablk + m * 1024 + kc * 64 + sloc * 8;
        __builtin_amdgcn_global_load_lds(AS1C(gp),
                                         AS3((char*)as + ii * 4096 + w * 1024),
                                         16, 0, 0);
      }
      __syncthreads();  // as (and xs) visible
#pragma unroll
      for (int ks = 0; ks < 2; ++ks) {
        bf16x8 af[4];
#pragma unroll
        for (int mt = 0; mt < 4; ++mt) {
          int m  = wm * 64 + mt * 16 + lm;
          int sp = (ks * 4 + q) ^ (m & 7);
          af[mt] = *(const bf16x8*)((const char*)as + m * 128 + sp * 16);
        }
        const int crow = kc * 4 + ks * 2 + (q >> 1);
        const char* xrow = (const char*)xs + crow * 560 + 16 * (q & 1);
#pragma unroll
        for (int nt = 0; nt < 4; ++nt) {
          int n = wn * 64 + nt * 16 + lm;
          const char* bp = xrow + 4 * n;
          union { u32 u[4]; bf16x8 v; } bb;
#pragma unroll
          for (int ww = 0; ww < 4; ++ww)
            bb.u[ww] = *(const u32*)(bp + 4 * ww);
#pragma unroll
          for (int mt = 0; mt < 4; ++mt)
            acc[mt][nt] = __builtin_amdgcn_mfma_f32_16x16x32_bf16(
                af[mt], bb.v, acc[mt][nt], 0, 0, 0);
        }
      }
    }
  }

  // epilogue: bias + leaky relu, D layout: row=(q*4+reg), col=lm per 16x16 tile
  const float* bgp = biasg + g * 128 + wm * 64;
  float* outb = out + ((size_t)b * 1536 + g * 128 + wm * 64) * 2048 + t0 + wn * 64;
#pragma unroll
  for (int mt = 0; mt < 4; ++mt) {
    const f32x4 bv = *(const f32x4*)(bgp + mt * 16 + q * 4);
#pragma unroll
    for (int reg = 0; reg < 4; ++reg) {
      const float bias = bv[reg];
      const int m = mt * 16 + q * 4 + reg;
      float* orow = outb + (size_t)m * 2048 + lm;
#pragma unroll
      for (int nt = 0; nt < 4; ++nt) {
        float v = acc[mt][nt][reg] + bias;
        orow[nt * 16] = v < 0.f ? 0.2f * v : v;
      }
    }
  }
}

// ---------------------------------------------------------------------------
extern "C" void kernel_launch(void* const* d_in, const int* in_sizes, int n_in,
                              void* d_out, int out_size, void* d_ws, size_t ws_size,
                              hipStream_t stream) {
  (void)in_sizes; (void)n_in; (void)out_size; (void)ws_size;
  const float* x   = (const float*)d_in[0];
  const float* wt  = (const float*)d_in[1];
  const float* bs  = (const float*)d_in[2];
  const float* msk = (const float*)d_in[3];
  // d_in[4] (pool_w): structure hardcoded, values (1/len) folded via d_gscale.

  u16*   xpbf = (u16*)d_ws;                                   // 88,424,448 B
  u16*   apk  = (u16*)((char*)d_ws + 88424448);               // 22,282,240 B
  float* bg   = (float*)((char*)d_ws + 110706688);            //      6,144 B
  float* out  = (float*)d_out;

  prep_x<<<dim3(21588), dim3(256), 0, stream>>>(x, xpbf);
  prep_w<<<dim3(2720),  dim3(256), 0, stream>>>(wt, msk, apk);
  prep_b<<<dim3(6),     dim3(256), 0, stream>>>(bs, bg);
  conv_main<<<dim3(1536), dim3(256), 0, stream>>>(xpbf, apk, bg, out);
}

// Round 14
// 780.241 us; speedup vs baseline: 1.2603x; 1.0025x over previous
//
#include <hip/hip_runtime.h>
#include <cstdint>
#include <cstddef>

typedef unsigned short u16;
typedef unsigned int   u32;

typedef __bf16 bf16x8 __attribute__((ext_vector_type(8)));
typedef float  f32x4  __attribute__((ext_vector_type(4)));

#define AS1C(p) ((const __attribute__((address_space(1))) void*)(p))
#define AS3(p)  ((__attribute__((address_space(3))) void*)(p))

// ---------------------------------------------------------------------------
// Hardcoded graph structure (derived from EDGES, SKELETON_DIST=2, pooling):
// 12 pooling groups; per-group input-joint block lists (85 slots total).
// Safety: prep_w still multiplies by the mask block value, so an extra block
// listed here would contribute exactly 0.
// ---------------------------------------------------------------------------
__constant__ int d_slot_jb[85] = {
  0,1,2,12,13,16,17,20,                 // g0  (8)
  0,1,2,3,4,5,8,9,12,16,20,            // g1  (11)
  1,2,3,4,5,8,9,                       // g2  (7)
  1,2,3,4,5,6,7,8,9,                   // g3  (9)
  4,5,6,7,                             // g4  (4)
  1,2,3,4,5,8,9,10,11,                 // g5  (9)
  8,9,10,11,                           // g6  (4)
  0,1,12,13,14,15,16,17,20,            // g7  (9)
  12,13,14,15,                         // g8  (4)
  0,1,12,13,16,17,18,19,20,            // g9  (9)
  16,17,18,19,                         // g10 (4)
  0,1,2,12,13,16,17                    // g11 (7)
};
__constant__ int   d_gs0[12]    = {0,8,19,26,35,39,48,52,61,65,74,78};
__constant__ int   d_gnb[12]    = {8,11,7,9,4,9,4,9,4,9,4,7};
__constant__ int   d_gj0[12]    = {0,1,3,4,6,8,10,12,14,16,18,20};
__constant__ int   d_gj1[12]    = {-1,2,-1,5,7,9,11,13,15,17,19,-1};
__constant__ float d_gscale[12] = {1.f,0.5f,1.f,0.5f,0.5f,0.5f,0.5f,0.5f,0.5f,0.5f,0.5f,1.f};
// heavy groups first to reduce tail imbalance
__constant__ int   d_sched[12]  = {1,3,5,7,9,0,2,11,4,6,8,10};

static __device__ __forceinline__ u16 f2bf(float f) {
  union { float f; u32 u; } v; v.f = f;
  u32 r = v.u + 0x7fffu + ((v.u >> 16) & 1u);   // RNE
  return (u16)(r >> 16);
}

// ---------------------------------------------------------------------------
// P1: x (8,1344,4096) fp32 -> reflect-padded bf16 xp (8,1344,4112 pitch)
// ---------------------------------------------------------------------------
__global__ void prep_x(const float* __restrict__ x, u16* __restrict__ xp) {
  int gid = blockIdx.x * 256 + threadIdx.x;          // 8*1344*514 threads
  if (gid >= 8 * 1344 * 514) return;
  int pc  = gid % 514;
  int row = gid / 514;
  int p   = pc * 8;
  const float* xr = x + (size_t)row * 4096;
  u16 v[8];
  if (p >= 8 && p <= 4088) {               // j = p-7..p, all interior
    const float* bse = xr + p - 7;
#pragma unroll
    for (int e = 0; e < 8; ++e) v[e] = f2bf(bse[e]);
  } else {
#pragma unroll
    for (int e = 0; e < 8; ++e) {
      int j = p + e - 7;
      j = j < 0 ? -j : (j > 4095 ? 8190 - j : j);
      v[e] = f2bf(xr[j]);
    }
  }
  *(uint4*)(xp + (size_t)row * 4112 + p) = *(const uint4*)v;
}

// ---------------------------------------------------------------------------
// P2: packed folded weights A[u][m=128][kk=1024] bf16,
//     kk = c*16 + tap (tap 15 = zero pad), u = global block slot (85).
//     A = gscale * sum_{j in group} maskblk(j,jb) * weight[j*128+m][jb*64+c][tap]
// ---------------------------------------------------------------------------
__global__ void prep_w(const float* __restrict__ wt, const float* __restrict__ msk,
                       u16* __restrict__ apk) {
  int gid = blockIdx.x * 256 + threadIdx.x;          // 85*8192 threads
  if (gid >= 85 * 8192) return;
  int u   = gid >> 13;
  int rem = gid & 8191;
  int m   = rem >> 6;
  int c   = rem & 63;
  int g = 11;
#pragma unroll
  for (int gg = 0; gg < 11; ++gg)
    if (u >= d_gs0[gg] && u < d_gs0[gg + 1]) g = gg;
  int jb = d_slot_jb[u];
  int j0 = d_gj0[g], j1 = d_gj1[g];
  float sc = d_gscale[g];
  float m0 = msk[((size_t)(j0 * 128) * 1344 + jb * 64) * 15];
  float m1 = (j1 >= 0) ? msk[((size_t)(j1 * 128) * 1344 + jb * 64) * 15] : 0.f;
  const float* w0 = wt + ((size_t)(j0 * 128 + m) * 1344 + jb * 64 + c) * 15;
  const float* w1 = (j1 >= 0) ? wt + ((size_t)(j1 * 128 + m) * 1344 + jb * 64 + c) * 15 : w0;
  u16 v[16];
#pragma unroll
  for (int k = 0; k < 15; ++k) {
    float a = m0 * w0[k] + m1 * w1[k];
    v[k] = f2bf(a * sc);
  }
  v[15] = 0;
  uint4* dst = (uint4*)(apk + (size_t)u * 131072 + m * 1024 + c * 16);
  dst[0] = ((const uint4*)v)[0];
  dst[1] = ((const uint4*)v)[1];
}

// ---------------------------------------------------------------------------
// P3: pooled bias (1536)
// ---------------------------------------------------------------------------
__global__ void prep_b(const float* __restrict__ bias, float* __restrict__ bg) {
  int pc = blockIdx.x * 256 + threadIdx.x;
  if (pc >= 1536) return;
  int g = pc >> 7, m = pc & 127;
  float v = bias[d_gj0[g] * 128 + m];
  if (d_gj1[g] >= 0) v += bias[d_gj1[g] * 128 + m];
  bg[pc] = v * d_gscale[g];
}

// ---------------------------------------------------------------------------
// Main: R0-proven barrier schedule (stage -> barrier -> compute, 2 barriers
// per kk=64 chunk), with the B-operand read restructured.
// DIAGNOSIS (R13 counters + m134 cycle constants): conv was LDS-read-pipe
// bound: bb as 4x ds_read_b32 per fragment (4-B aligned, 4x byte redundancy)
// = 185.6 cy/chunk-wave vs af 96 cy; total ~319 us ~= measured 325 us.
// FIX: column-interleaved fragments. Fragment nt owns columns
// {wn*64 + 4*lm + nt}; one lane's data for all 4 nt = dwords [4lm..4lm+7]
// of the (crow, q&1, wn) window = TWO 16-B-ALIGNED ds_read_b128. Fragment
// operands are then compile-time register selects wreg.u[nt..nt+3] (VALU,
// which has headroom). bb LDS cost 185.6 -> 48 cy/chunk-wave. Numerics:
// same MFMAs modulo intra-tile column permutation, inverted in the epilogue
// (col = wn*64 + 4*lm + nt). No sync changes.
// ---------------------------------------------------------------------------
__global__ __launch_bounds__(256, 3)
void conv_main(const u16* __restrict__ xpbf, const u16* __restrict__ apk,
               const float* __restrict__ biasg, float* __restrict__ out) {
  __shared__ __align__(16) u16 xs[64 * 280];   // pitch 280 bf16 (560 B)
  __shared__ __align__(16) u16 as[128 * 64];   // 16 KB: rows m, 8 swizzled 16B segs

  const int tid = threadIdx.x;
  const int l   = tid & 63, w = tid >> 6;
  const int q   = l >> 4, lm = l & 15;
  const int wm  = w & 1, wn = w >> 1;

  const int gidx = blockIdx.x >> 7;
  const int g    = d_sched[gidx];
  const int r    = blockIdx.x & 127;
  const int b    = r >> 4;
  const int tile = r & 15;
  const int t0   = tile << 7;
  const int p0   = t0 << 1;

  const int nb = d_gnb[g];
  const int s0 = d_gs0[g];

  f32x4 acc[4][4];
#pragma unroll
  for (int i = 0; i < 4; ++i)
#pragma unroll
    for (int j = 0; j < 4; ++j)
      acc[i][j] = (f32x4){0.f, 0.f, 0.f, 0.f};

  const int as_mb = tid >> 3;   // + ii*32
  const int as_sp = tid & 7;

  // B window base for this lane: row crow picked per (kc,ks,q>>1); within a
  // row: + 16*(q&1) tap-half + 256*wn col-block + 16*lm lane dword-quad.
  const char* xwin = (const char*)xs + 16 * (q & 1) + 256 * wn + 16 * lm;

  for (int s = 0; s < nb; ++s) {
    const int u  = s0 + s;
    const int jb = d_slot_jb[u];
    __syncthreads();  // xs from previous block fully consumed
    {
      const u16* srow = xpbf + (size_t)(b * 1344 + jb * 64) * 4112 + p0;
      for (int i = tid; i < 64 * 34; i += 256) {
        int c  = i / 34;
        int sg = i - c * 34;
        uint4 v = *(const uint4*)(srow + (size_t)c * 4112 + sg * 8);
        *(uint4*)((char*)xs + c * 560 + sg * 16) = v;
      }
    }
    const u16* ablk = apk + (size_t)u * 131072;
    for (int kc = 0; kc < 16; ++kc) {
      __syncthreads();  // prev chunk of `as` consumed; (kc==0) xs writes ordered
#pragma unroll
      for (int ii = 0; ii < 4; ++ii) {
        int m    = ii * 32 + as_mb;
        int sloc = as_sp ^ (m & 7);
        const u16* gp = ablk + m * 1024 + kc * 64 + sloc * 8;
        __builtin_amdgcn_global_load_lds(AS1C(gp),
                                         AS3((char*)as + ii * 4096 + w * 1024),
                                         16, 0, 0);
      }
      __syncthreads();  // as (and xs) visible
#pragma unroll
      for (int ks = 0; ks < 2; ++ks) {
        bf16x8 af[4];
#pragma unroll
        for (int mt = 0; mt < 4; ++mt) {
          int m  = wm * 64 + mt * 16 + lm;
          int sp = (ks * 4 + q) ^ (m & 7);
          af[mt] = *(const bf16x8*)((const char*)as + m * 128 + sp * 16);
        }
        const int crow = kc * 4 + ks * 2 + (q >> 1);
        // two aligned b128 covering dwords [4lm .. 4lm+7] of this row window
        union { u32 u[8]; uint4 v[2]; } wreg;
        wreg.v[0] = *(const uint4*)(xwin + crow * 560);
        wreg.v[1] = *(const uint4*)(xwin + crow * 560 + 16);
#pragma unroll
        for (int nt = 0; nt < 4; ++nt) {
          union { u32 u[4]; bf16x8 v; } bb;
          bb.u[0] = wreg.u[nt];
          bb.u[1] = wreg.u[nt + 1];
          bb.u[2] = wreg.u[nt + 2];
          bb.u[3] = wreg.u[nt + 3];
#pragma unroll
          for (int mt = 0; mt < 4; ++mt)
            acc[mt][nt] = __builtin_amdgcn_mfma_f32_16x16x32_bf16(
                af[mt], bb.v, acc[mt][nt], 0, 0, 0);
        }
      }
    }
  }

  // epilogue: bias + leaky relu. D layout per 16x16 tile: row=(q*4+reg),
  // fragment-col=lm; fragment nt's column set is {4*lm + nt} (interleaved).
  const float* bgp = biasg + g * 128 + wm * 64;
  float* outb = out + ((size_t)b * 1536 + g * 128 + wm * 64) * 2048 + t0 + wn * 64;
#pragma unroll
  for (int mt = 0; mt < 4; ++mt) {
    const f32x4 bv = *(const f32x4*)(bgp + mt * 16 + q * 4);
#pragma unroll
    for (int reg = 0; reg < 4; ++reg) {
      const float bias = bv[reg];
      const int m = mt * 16 + q * 4 + reg;
      float* orow = outb + (size_t)m * 2048 + 4 * lm;
#pragma unroll
      for (int nt = 0; nt < 4; ++nt) {
        float v = acc[mt][nt][reg] + bias;
        orow[nt] = v < 0.f ? 0.2f * v : v;
      }
    }
  }
}

// ---------------------------------------------------------------------------
extern "C" void kernel_launch(void* const* d_in, const int* in_sizes, int n_in,
                              void* d_out, int out_size, void* d_ws, size_t ws_size,
                              hipStream_t stream) {
  (void)in_sizes; (void)n_in; (void)out_size; (void)ws_size;
  const float* x   = (const float*)d_in[0];
  const float* wt  = (const float*)d_in[1];
  const float* bs  = (const float*)d_in[2];
  const float* msk = (const float*)d_in[3];
  // d_in[4] (pool_w): structure hardcoded, values (1/len) folded via d_gscale.

  u16*   xpbf = (u16*)d_ws;                                   // 88,424,448 B
  u16*   apk  = (u16*)((char*)d_ws + 88424448);               // 22,282,240 B
  float* bg   = (float*)((char*)d_ws + 110706688);            //      6,144 B
  float* out  = (float*)d_out;

  prep_x<<<dim3(21588), dim3(256), 0, stream>>>(x, xpbf);
  prep_w<<<dim3(2720),  dim3(256), 0, stream>>>(wt, msk, apk);
  prep_b<<<dim3(6),     dim3(256), 0, stream>>>(bs, bg);
  conv_main<<<dim3(1536), dim3(256), 0, stream>>>(xpbf, apk, bg, out);
}